// Round 8
// baseline (365.460 us; speedup 1.0000x reference)
//
#include <hip/hip_runtime.h>
#include <math.h>

#define B 2
#define T 2048
#define D 2048
#define H 16
#define KV 4
#define HD 128
#define REP (H / KV)

typedef __attribute__((ext_vector_type(8))) short bf16x8;
typedef __attribute__((ext_vector_type(4))) short bf16x4;
typedef __attribute__((ext_vector_type(4))) float f32x4;
typedef __attribute__((ext_vector_type(2))) unsigned int u32x2;

// 1/sqrt(128) * log2(e): scores land in log2 domain -> exp2f softmax.
// With RMSNorm'd q,k (w=1): |s| <= 128*QSCALE = 16.33 -> static-max softmax
// is safe (exp2 <= 8.2e4, l <= 1.8e8, fp32-exact enough).
#define QSCALE 0.1275177f

__device__ __forceinline__ short f2bf(float f) {
    unsigned int u = __float_as_uint(f);
    unsigned int r = (u + 0x7fffu + ((u >> 16) & 1u)) >> 16;
    return (short)r;
}
__device__ __forceinline__ float bf2f(short s) {
    return __uint_as_float(((unsigned int)(unsigned short)s) << 16);
}
__device__ __forceinline__ bf16x8 pack8(float4 a, float4 b, float s) {
    bf16x8 r;
    r[0] = f2bf(a.x * s); r[1] = f2bf(a.y * s); r[2] = f2bf(a.z * s); r[3] = f2bf(a.w * s);
    r[4] = f2bf(b.x * s); r[5] = f2bf(b.y * s); r[6] = f2bf(b.z * s); r[7] = f2bf(b.w * s);
    return r;
}
// pack two f32 -> (bf16(a) | bf16(b)<<16) by byte-perm (truncation, 1 instr)
__device__ __forceinline__ unsigned int pk_trunc(float a, float b) {
    return __builtin_amdgcn_perm(__float_as_uint(b), __float_as_uint(a), 0x07060302u);
}

#define GLD_LDS16(gp, lp) \
    __builtin_amdgcn_global_load_lds( \
        (const __attribute__((address_space(1))) void*)(gp), \
        (__attribute__((address_space(3))) void*)(lp), 16, 0, 0)

// ---------------------------------------------------------------------------
// Fused prep: x fp32->bf16 convert (blocks 0..4095) + wq/wk/wv transpose-cvt.
// ---------------------------------------------------------------------------
__global__ __launch_bounds__(256) void prep(
    const float* __restrict__ x, const float* __restrict__ wq,
    const float* __restrict__ wk, const float* __restrict__ wv,
    short* __restrict__ xb, short* __restrict__ wqT,
    short* __restrict__ wkT, short* __restrict__ wvT)
{
    int bid = blockIdx.x;
    if (bid < 4096) {
        int i = (bid * 256 + threadIdx.x) * 8;
        float4 a = *reinterpret_cast<const float4*>(x + i);
        float4 b2 = *reinterpret_cast<const float4*>(x + i + 4);
        *reinterpret_cast<bf16x8*>(xb + i) = pack8(a, b2, 1.0f);
        return;
    }
    bid -= 4096;
    const float* src; short* dst; int Kd, Nd, tn;
    if (bid < 4096)      { src = wq; dst = wqT; Kd = 2048; Nd = 2048; tn = bid; }
    else if (bid < 5120) { src = wk; dst = wkT; Kd = 2048; Nd = 512;  tn = bid - 4096; }
    else                 { src = wv; dst = wvT; Kd = 2048; Nd = 512;  tn = bid - 5120; }
    const int ntn = Nd / 32;
    const int k0 = (tn / ntn) * 32, n0 = (tn % ntn) * 32;
    __shared__ float tile[32][33];
    const int tx = threadIdx.x & 31, ty = threadIdx.x >> 5;
    #pragma unroll
    for (int i = 0; i < 4; ++i)
        tile[ty + i * 8][tx] = src[(size_t)(k0 + ty + i * 8) * Nd + n0 + tx];
    __syncthreads();
    #pragma unroll
    for (int i = 0; i < 4; ++i)
        dst[(size_t)(n0 + ty + i * 8) * Kd + k0 + tx] = f2bf(tile[tx][ty + i * 8]);
}

// ---------------------------------------------------------------------------
// bf16 MFMA GEMM (m97 structure): C[M,N] = A[M,K] @ Bt[N,K]^T.
// MODE 0: C fp32.
// MODE 4: fused QKV epilogue over N=3072 (wqT|wkT|wvT):
//   n0 <  2560 (Q and K tiles, each tile = ONE head's 128 hd-cols):
//     fused RMSNorm (fp32 acc, cross-lane reduce) + RoPE (lane-pair xor(1))
//     + QSCALE fold (Q only) + bf16 write. Replaces the norm_rope kernel.
//   n0 >= 2560 (V tiles): transposed bf16 write to vtb (as before).
// ---------------------------------------------------------------------------
template<int MODE>
__global__ __launch_bounds__(256) void gemm_bf16(
    const short* __restrict__ A, const short* __restrict__ Bt,
    void* __restrict__ Cv, void* __restrict__ Cv2, int M, int N, int K,
    const float* __restrict__ qw, const float* __restrict__ kw,
    const float* __restrict__ fc, const float* __restrict__ fs)
{
    __shared__ short As[128 * 32];
    __shared__ short Bs[128 * 32];

    const int tid  = threadIdx.x;
    const int w    = tid >> 6;
    const int lane = tid & 63;
    const int quad = lane >> 4;
    const int n16  = lane & 15;
    const int m0 = blockIdx.y * 128;
    const int n0 = blockIdx.x * 128;
    const int wm = (w >> 1) * 64;
    const int wn = (w & 1) * 64;

    f32x4 acc[4][4];
    #pragma unroll
    for (int i = 0; i < 4; ++i)
        #pragma unroll
        for (int j = 0; j < 4; ++j) acc[i][j] = (f32x4){0.f, 0.f, 0.f, 0.f};

    for (int k0 = 0; k0 < K; k0 += 32) {
        __syncthreads();
        #pragma unroll
        for (int c = 0; c < 2; ++c) {
            int f = c * 2048 + tid * 8;
            int r = f >> 5, cc = f & 31;
            GLD_LDS16(A  + (size_t)(m0 + r) * K + k0 + cc, As + c * 2048 + w * 512);
            GLD_LDS16(Bt + (size_t)(n0 + r) * K + k0 + cc, Bs + c * 2048 + w * 512);
        }
        __syncthreads();

        bf16x8 af[4], bf[4];
        #pragma unroll
        for (int i = 0; i < 4; ++i) {
            af[i] = *reinterpret_cast<const bf16x8*>(&As[(wm + i * 16 + n16) * 32 + quad * 8]);
            bf[i] = *reinterpret_cast<const bf16x8*>(&Bs[(wn + i * 16 + n16) * 32 + quad * 8]);
        }
        #pragma unroll
        for (int mi = 0; mi < 4; ++mi)
            #pragma unroll
            for (int ni = 0; ni < 4; ++ni)
                acc[mi][ni] = __builtin_amdgcn_mfma_f32_16x16x32_bf16(
                    af[mi], bf[ni], acc[mi][ni], 0, 0, 0);
    }

    if (MODE == 0) {
        float* C = (float*)Cv;
        #pragma unroll
        for (int mi = 0; mi < 4; ++mi)
            #pragma unroll
            for (int ni = 0; ni < 4; ++ni)
                #pragma unroll
                for (int r = 0; r < 4; ++r)
                    C[(size_t)(m0 + wm + mi * 16 + quad * 4 + r) * N
                      + n0 + wn + ni * 16 + n16] = acc[mi][ni][r];
    } else { // MODE 4
        if (n0 < 2560) {
            // ---- fused RMSNorm + RoPE (Q: n0<2048 scale=QSCALE; K: scale=1) ----
            const bool isQ = (n0 < 2048);
            const float* wnp = isQ ? qw : kw;
            const float scale = isQ ? QSCALE : 1.0f;

            // per-thread partial sum-of-squares (4 cols) for 16 rows
            float ssp[4][4];
            #pragma unroll
            for (int mi = 0; mi < 4; ++mi)
                #pragma unroll
                for (int r = 0; r < 4; ++r) {
                    float sx = 0.f;
                    #pragma unroll
                    for (int ni = 0; ni < 4; ++ni)
                        sx += acc[mi][ni][r] * acc[mi][ni][r];
                    ssp[mi][r] = sx;
                }
            // butterfly over the 16 n16-lanes (stays within quad)
            #pragma unroll
            for (int off = 8; off; off >>= 1)
                #pragma unroll
                for (int mi = 0; mi < 4; ++mi)
                    #pragma unroll
                    for (int r = 0; r < 4; ++r)
                        ssp[mi][r] += __shfl_xor(ssp[mi][r], off);
            // cross wave-pair (wn=0 <-> wn=64) via LDS (reuse As, dead now)
            float* SS = (float*)As;   // [2][128]
            __syncthreads();
            if (n16 == 0)
                #pragma unroll
                for (int mi = 0; mi < 4; ++mi)
                    #pragma unroll
                    for (int r = 0; r < 4; ++r)
                        SS[(w & 1) * 128 + wm + mi * 16 + quad * 4 + r] = ssp[mi][r];
            __syncthreads();

            short* Cq = (short*)Cv;
            short* Ck = (short*)Cv2;
            #pragma unroll
            for (int mi = 0; mi < 4; ++mi) {
                #pragma unroll
                for (int r = 0; r < 4; ++r) {
                    const int row  = wm + mi * 16 + quad * 4 + r;
                    const int mrow = m0 + row;
                    const int t    = mrow & (T - 1);
                    const float ss = SS[row] + SS[128 + row];
                    const float rinv = rsqrtf(ss * (1.0f / HD) + 1e-6f);
                    #pragma unroll
                    for (int ni = 0; ni < 4; ++ni) {
                        const int col = wn + ni * 16 + n16;     // 0..127 in head
                        float v = acc[mi][ni][r] * rinv * wnp[col];
                        const float prt = __shfl_xor(v, 1);     // partner col^1
                        const int j = col >> 1;
                        const float c  = fc[t * (HD / 2) + j];
                        const float sn = fs[t * (HD / 2) + j];
                        // even col: e=v, o=prt -> e*c - o*s
                        // odd  col: e=prt, o=v -> e*s + o*c
                        float outv = (n16 & 1) ? (prt * sn + v * c)
                                               : (v * c - prt * sn);
                        outv *= scale;
                        if (isQ)
                            Cq[(size_t)mrow * 2048 + n0 + col] = f2bf(outv);
                        else
                            Ck[(size_t)mrow * 512 + (n0 - 2048) + col] = f2bf(outv);
                    }
                }
            }
        } else {
            // ---- V tiles: transposed bf16 write to vtb ----
            short* Cvt = (short*)Cv2 + (size_t)B * T * KV * HD;  // vtb after kbuf
            #pragma unroll
            for (int mi = 0; mi < 4; ++mi) {
                int mrow = m0 + wm + mi * 16 + quad * 4;
                int bb = mrow >> 11;
                int t0 = mrow & (T - 1);
                #pragma unroll
                for (int ni = 0; ni < 4; ++ni) {
                    int n = n0 + wn + ni * 16 + n16 - 2048;   // 512..1023
                    bf16x4 p;
                    p[0] = f2bf(acc[mi][ni][0]); p[1] = f2bf(acc[mi][ni][1]);
                    p[2] = f2bf(acc[mi][ni][2]); p[3] = f2bf(acc[mi][ni][3]);
                    *reinterpret_cast<bf16x4*>(
                        &Cvt[((size_t)bb * 512 + (n - 512)) * T + t0]) = p;
                }
            }
        }
    }
}

// ---------------------------------------------------------------------------
// MFMA flash attention v10 = v9 attention path (verified 88.5us) + wo
// transpose-cvt folded in as blocks 512..2559 (2 tiles of 32x32 per block,
// reusing Ks LDS -> LDS footprint unchanged, 2 blocks/CU preserved).
// attn blocks are first in the grid: the critical qb=15 block starts at t=0;
// transpose blocks backfill idle CU slots.
// ---------------------------------------------------------------------------
__global__ __launch_bounds__(512, 4) void attn_mfma(
    short* qob, const short* __restrict__ kb_, const short* __restrict__ vtb,
    const float* __restrict__ wo_, short* __restrict__ woT_)
{
    __shared__ short Ks[2][64 * 128];   // 32KB: [key][hd], 16B-chunk swz by key&7
    __shared__ short Vt[2][128 * 64];   // 32KB: [hd][key], 16B-chunk swz by hd&7
    __shared__ short Pl[4][32 * 64];    // 8KB

    const int tid = threadIdx.x;
    const int bid = blockIdx.x;

    if (bid >= 512) {
        // ---- wo transpose-cvt: 2048 blocks x 2 tiles (32x32), 512 threads ----
        float* tileb = reinterpret_cast<float*>(&Ks[0][0]);   // 2 x 32x33 f32
        const int half = tid >> 8;
        const int tl   = tid & 255;
        const int tx = tl & 31, ty = tl >> 5;                 // ty 0..7
        const int tn = (bid - 512) * 2 + half;                // 0..4095
        const int k0 = (tn >> 6) * 32, n0t = (tn & 63) * 32;
        float* tile = tileb + half * (32 * 33);
        #pragma unroll
        for (int i = 0; i < 4; ++i)
            tile[(ty + i * 8) * 33 + tx] =
                wo_[(size_t)(k0 + ty + i * 8) * 2048 + n0t + tx];
        __syncthreads();
        #pragma unroll
        for (int i = 0; i < 4; ++i)
            woT_[(size_t)(n0t + ty + i * 8) * 2048 + k0 + tx] =
                f2bf(tile[tx * 33 + ty + i * 8]);
        return;
    }

    const int w    = tid >> 6;      // 0..7
    const int w4   = w & 3;         // q-group (32 q-rows)
    const int kh   = w >> 2;        // half-split index
    const int lane = tid & 63;
    const int q4   = lane >> 4;
    const int n16  = lane & 15;

    int qb;
    if (bid < 256) qb = 15 - (bid >> 5);    // heavy half: qb 15..8
    else           qb = (bid - 256) >> 5;   // light half: qb 0..7
    const int h = bid & 15;
    const int b = (bid >> 4) & 1;
    const int g = h >> 2;

    // Q fragments (B-operand): 2 m-sets of 16 queries, QSCALE pre-folded
    bf16x8 qf[2][4];
    #pragma unroll
    for (int m = 0; m < 2; ++m) {
        const int qrow = qb * 128 + w4 * 32 + m * 16 + n16;
        const short* qp = qob + ((size_t)(b * T + qrow) * H + h) * HD;
        #pragma unroll
        for (int c = 0; c < 4; ++c)
            qf[m][c] = *reinterpret_cast<const bf16x8*>(qp + c * 32 + q4 * 8);
    }

    f32x4 oa[2][4];
    #pragma unroll
    for (int m = 0; m < 2; ++m)
        #pragma unroll
        for (int nl = 0; nl < 4; ++nl) oa[m][nl] = (f32x4){0.f, 0.f, 0.f, 0.f};
    float l0 = 0.f, l1 = 0.f;

    short* preg = &Pl[w4][0];

    // staging lane mapping (512 threads, 2 issues each of K and V per iter)
    const int kr  = lane >> 4;                  // K: 4 rows per wave-issue
    const int kc_ = lane & 15;
    const int vr  = lane >> 3;                  // V: 8 rows per wave-issue
    const int vc_ = lane & 7;

    const short* kgb = kb_ + (size_t)b * T * KV * HD + (size_t)g * HD;
    const short* vgb = vtb + ((size_t)(b * KV + g) * HD) * T;

    auto STAGE_K = [&](int bb, int kb) {
        short* KsB = &Ks[bb][0];
        #pragma unroll
        for (int i = 0; i < 2; ++i) {
            const int grow = (i * 8 + w) * 4 + kr;          // 0..63
            const int cs   = kc_ ^ (grow & 7);
            GLD_LDS16(kgb + (size_t)(kb * 64 + grow) * (KV * HD) + cs * 8,
                      KsB + (i * 8 + w) * 512);
        }
    };
    auto STAGE_V = [&](int bb, int kb) {
        short* VtB = &Vt[bb][0];
        #pragma unroll
        for (int i = 0; i < 2; ++i) {
            const int hd = (i * 8 + w) * 8 + vr;            // 0..127
            const int cs = vc_ ^ (hd & 7);
            GLD_LDS16(vgb + (size_t)hd * T + kb * 64 + cs * 8,
                      VtB + (i * 8 + w) * 512);
        }
    };

    const int nkb = 2 * qb + 2;  // 64-key tiles covering keys [0, (qb+1)*128)
    int cur = 0;

    // prologue: stage K(0), V(0), drain, sync
    STAGE_K(0, 0);
    STAGE_V(0, 0);
    asm volatile("s_waitcnt vmcnt(0)" ::: "memory");
    __builtin_amdgcn_sched_barrier(0);
    __builtin_amdgcn_s_barrier();
    __builtin_amdgcn_sched_barrier(0);

    for (int kb = 0; kb < nkb; ++kb) {
        // issue next tile's K AND V into the other buffer (drained at end bar)
        const bool pf = (kb + 1 < nkb);
        if (pf) {
            STAGE_V(cur ^ 1, kb + 1);
            STAGE_K(cur ^ 1, kb + 1);
        }

        const int kof = kb * 64 - qb * 128;   // local key offset (>=0 only near diag)
        const short* KsB = &Ks[cur][0];
        const short* VtB = &Vt[cur][0];

        // ---- S^T = K @ Q^T over this wave's key-half (kt = kh*2 + kt') ----
        f32x4 s[2][2];
        #pragma unroll
        for (int m = 0; m < 2; ++m)
            #pragma unroll
            for (int kt = 0; kt < 2; ++kt) s[m][kt] = (f32x4){0.f, 0.f, 0.f, 0.f};

        __builtin_amdgcn_s_setprio(1);
        #pragma unroll
        for (int cc = 0; cc < 4; ++cc) {
            const int gk = (4 * cc + q4) ^ (n16 & 7);
            #pragma unroll
            for (int kt = 0; kt < 2; ++kt) {
                const int ktg = kh * 2 + kt;
                bf16x8 kf = *reinterpret_cast<const bf16x8*>(
                    &KsB[(ktg * 16 + n16) * 128 + gk * 8]);
                if (!(kof + ktg * 16 > w4 * 32 + 15))
                    s[0][kt] = __builtin_amdgcn_mfma_f32_16x16x32_bf16(kf, qf[0][cc], s[0][kt], 0, 0, 0);
                if (!(kof + ktg * 16 > w4 * 32 + 31))
                    s[1][kt] = __builtin_amdgcn_mfma_f32_16x16x32_bf16(kf, qf[1][cc], s[1][kt], 0, 0, 0);
            }
        }
        __builtin_amdgcn_s_setprio(0);

        // ---- causal mask (diagonal tiles only) ----
        if (kof >= 0) {
            #pragma unroll
            for (int m = 0; m < 2; ++m) {
                const int qloc = w4 * 32 + m * 16 + n16;
                #pragma unroll
                for (int kt = 0; kt < 2; ++kt)
                    #pragma unroll
                    for (int r = 0; r < 4; ++r)
                        if (kof + (kh * 2 + kt) * 16 + q4 * 4 + r > qloc)
                            s[m][kt][r] = -1e30f;
            }
        }

        // ---- static-max softmax in place: s := exp2(s); accumulate l ----
        #pragma unroll
        for (int kt = 0; kt < 2; ++kt) {
            #pragma unroll
            for (int r = 0; r < 4; ++r) {
                s[0][kt][r] = exp2f(s[0][kt][r]);
                s[1][kt][r] = exp2f(s[1][kt][r]);
            }
            l0 += (s[0][kt][0] + s[0][kt][1]) + (s[0][kt][2] + s[0][kt][3]);
            l1 += (s[1][kt][0] + s[1][kt][1]) + (s[1][kt][2] + s[1][kt][3]);
        }

        // ---- pack P -> shared per-q-group buffer (this wave's key-half) ----
        #pragma unroll
        for (int m = 0; m < 2; ++m) {
            const int row = m * 16 + n16;
            #pragma unroll
            for (int kt = 0; kt < 2; ++kt) {
                const int c = kh * 4 + kt * 2 + (q4 >> 1);
                u32x2 wv;
                wv[0] = pk_trunc(s[m][kt][0], s[m][kt][1]);
                wv[1] = pk_trunc(s[m][kt][2], s[m][kt][3]);
                *reinterpret_cast<u32x2*>(
                    &preg[row * 64 + (c ^ (n16 & 7)) * 8 + (q4 & 1) * 4]) = wv;
            }
        }

        // ---- mid barrier (drain-free): P visible to partner wave ----
        asm volatile("s_waitcnt lgkmcnt(0)" ::: "memory");
        __builtin_amdgcn_sched_barrier(0);
        __builtin_amdgcn_s_barrier();
        __builtin_amdgcn_sched_barrier(0);

        // ---- P @ V: full 64 keys, this wave's hd-half (nt = kh*4 + nl) ----
        __builtin_amdgcn_s_setprio(1);
        #pragma unroll
        for (int kc = 0; kc < 2; ++kc) {
            const bool u0 = !(kof + kc * 32 > w4 * 32 + 15);
            const bool u1 = !(kof + kc * 32 > w4 * 32 + 31);
            if (u0 | u1) {
                const int gp = ((kc * 4 + q4) ^ (n16 & 7)) * 8;
                bf16x8 af0 = *reinterpret_cast<const bf16x8*>(&preg[n16 * 64 + gp]);
                bf16x8 af1 = *reinterpret_cast<const bf16x8*>(&preg[(16 + n16) * 64 + gp]);
                #pragma unroll
                for (int nl = 0; nl < 4; ++nl) {
                    const int nt = kh * 4 + nl;
                    bf16x8 vf = *reinterpret_cast<const bf16x8*>(
                        &VtB[(nt * 16 + n16) * 64 + gp]);
                    if (u0)
                        oa[0][nl] = __builtin_amdgcn_mfma_f32_16x16x32_bf16(af0, vf, oa[0][nl], 0, 0, 0);
                    if (u1)
                        oa[1][nl] = __builtin_amdgcn_mfma_f32_16x16x32_bf16(af1, vf, oa[1][nl], 0, 0, 0);
                }
            }
        }
        __builtin_amdgcn_s_setprio(0);

        // ---- end barrier: next tile's K+V landed; buffers release ----
        asm volatile("s_waitcnt vmcnt(0)" ::: "memory");
        __builtin_amdgcn_sched_barrier(0);
        __builtin_amdgcn_s_barrier();
        __builtin_amdgcn_sched_barrier(0);
        cur ^= 1;
    }

    // ---- epilogue: reduce l over q4, combine key-halves, O = oa / l ----
    l0 += __shfl_xor(l0, 16); l0 += __shfl_xor(l0, 32);
    l1 += __shfl_xor(l1, 16); l1 += __shfl_xor(l1, 32);

    float* Lsh = (float*)&Pl[0][0];
    if (q4 == 0) {
        Lsh[w * 32 + n16] = l0;
        Lsh[w * 32 + 16 + n16] = l1;
    }
    __syncthreads();
    l0 += Lsh[(w ^ 4) * 32 + n16];
    l1 += Lsh[(w ^ 4) * 32 + 16 + n16];

    #pragma unroll
    for (int m = 0; m < 2; ++m) {
        #pragma unroll
        for (int r = 0; r < 4; ++r) {
            const float lr = __shfl(m == 0 ? l0 : l1, q4 * 20 + r);
            const float inv = 1.0f / lr;
            const int row = qb * 128 + w4 * 32 + m * 16 + q4 * 4 + r;
            short* op = qob + ((size_t)(b * T + row) * H + h) * HD;
            #pragma unroll
            for (int nl = 0; nl < 4; ++nl)
                op[(kh * 4 + nl) * 16 + n16] = f2bf(oa[m][nl][r] * inv);
        }
    }
}

// ---------------------------------------------------------------------------
extern "C" void kernel_launch(void* const* d_in, const int* in_sizes, int n_in,
                              void* d_out, int out_size, void* d_ws, size_t ws_size,
                              hipStream_t stream) {
    const float* x  = (const float*)d_in[0];
    const float* wq = (const float*)d_in[1];
    const float* wk = (const float*)d_in[2];
    const float* wv = (const float*)d_in[3];
    const float* wo = (const float*)d_in[4];
    const float* qw = (const float*)d_in[5];
    const float* kw = (const float*)d_in[6];
    const float* fc = (const float*)d_in[7];
    const float* fs = (const float*)d_in[8];
    float* out = (float*)d_out;

    short* xb   = (short*)d_ws;                      // B*T*D
    short* wqT  = xb   + (size_t)B * T * D;          // D*D
    short* wkT  = wqT  + (size_t)D * D;              // 512*D (contiguous after wqT)
    short* wvT  = wkT  + (size_t)(KV * HD) * D;      // 512*D (contiguous after wkT)
    short* qbuf = wvT  + (size_t)(KV * HD) * D;      // B*T*H*HD
    short* kbuf = qbuf + (size_t)B * T * H * HD;     // B*T*KV*HD
    short* vtb  = kbuf + (size_t)B * T * KV * HD;    // B*KV*HD*T (contiguous after kbuf)
    short* woT  = xb;                                // alias: xb dead after QKV GEMM

    const int M = B * T;   // 4096
    dim3 blk(256);

    // 1) prep: x convert + wq/wk/wv transpose
    prep<<<dim3(10240), blk, 0, stream>>>(x, wq, wk, wv, xb, wqT, wkT, wvT);

    // 2) fused Q|K|V GEMM + RMSNorm + RoPE epilogue (norm_rope eliminated)
    gemm_bf16<4><<<dim3(3072 / 128, M / 128), blk, 0, stream>>>(
        xb, wqT, (void*)qbuf, (void*)kbuf, M, 3072, D, qw, kw, fc, fs);

    // 3) attention + wo transpose-cvt (blocks 512..2559)
    attn_mfma<<<dim3(2560), dim3(512), 0, stream>>>(qbuf, kbuf, vtb, wo, woT);

    // 4) output GEMM
    gemm_bf16<0><<<dim3(D / 128, M / 128), blk, 0, stream>>>(
        qbuf, woT, (void*)out, nullptr, M, D, H * HD,
        nullptr, nullptr, nullptr, nullptr);
}

// Round 9
// 338.550 us; speedup vs baseline: 1.0795x; 1.0795x over previous
//
#include <hip/hip_runtime.h>
#include <math.h>

#define B 2
#define T 2048
#define D 2048
#define H 16
#define KV 4
#define HD 128
#define REP (H / KV)

typedef __attribute__((ext_vector_type(8))) short bf16x8;
typedef __attribute__((ext_vector_type(4))) short bf16x4;
typedef __attribute__((ext_vector_type(4))) float f32x4;
typedef __attribute__((ext_vector_type(2))) unsigned int u32x2;

// 1/sqrt(128) * log2(e): scores land in log2 domain -> exp2f softmax.
// With RMSNorm'd q,k (w=1): |s| <= 128*QSCALE = 16.33 -> static-max softmax
// is safe (exp2 <= 8.2e4, l <= 1.8e8, fp32-exact enough).
#define QSCALE 0.1275177f

__device__ __forceinline__ short f2bf(float f) {
    unsigned int u = __float_as_uint(f);
    unsigned int r = (u + 0x7fffu + ((u >> 16) & 1u)) >> 16;
    return (short)r;
}
__device__ __forceinline__ float bf2f(short s) {
    return __uint_as_float(((unsigned int)(unsigned short)s) << 16);
}
__device__ __forceinline__ bf16x8 pack8(float4 a, float4 b, float s) {
    bf16x8 r;
    r[0] = f2bf(a.x * s); r[1] = f2bf(a.y * s); r[2] = f2bf(a.z * s); r[3] = f2bf(a.w * s);
    r[4] = f2bf(b.x * s); r[5] = f2bf(b.y * s); r[6] = f2bf(b.z * s); r[7] = f2bf(b.w * s);
    return r;
}
// pack two f32 -> (bf16(a) | bf16(b)<<16) by byte-perm (truncation, 1 instr)
__device__ __forceinline__ unsigned int pk_trunc(float a, float b) {
    return __builtin_amdgcn_perm(__float_as_uint(b), __float_as_uint(a), 0x07060302u);
}

#define GLD_LDS16(gp, lp) \
    __builtin_amdgcn_global_load_lds( \
        (const __attribute__((address_space(1))) void*)(gp), \
        (__attribute__((address_space(3))) void*)(lp), 16, 0, 0)

// ---------------------------------------------------------------------------
// Fused prep: x fp32->bf16 convert (blocks 0..4095) + wq/wk/wv transpose-cvt.
// ---------------------------------------------------------------------------
__global__ __launch_bounds__(256) void prep(
    const float* __restrict__ x, const float* __restrict__ wq,
    const float* __restrict__ wk, const float* __restrict__ wv,
    short* __restrict__ xb, short* __restrict__ wqT,
    short* __restrict__ wkT, short* __restrict__ wvT)
{
    int bid = blockIdx.x;
    if (bid < 4096) {
        int i = (bid * 256 + threadIdx.x) * 8;
        float4 a = *reinterpret_cast<const float4*>(x + i);
        float4 b2 = *reinterpret_cast<const float4*>(x + i + 4);
        *reinterpret_cast<bf16x8*>(xb + i) = pack8(a, b2, 1.0f);
        return;
    }
    bid -= 4096;
    const float* src; short* dst; int Kd, Nd, tn;
    if (bid < 4096)      { src = wq; dst = wqT; Kd = 2048; Nd = 2048; tn = bid; }
    else if (bid < 5120) { src = wk; dst = wkT; Kd = 2048; Nd = 512;  tn = bid - 4096; }
    else                 { src = wv; dst = wvT; Kd = 2048; Nd = 512;  tn = bid - 5120; }
    const int ntn = Nd / 32;
    const int k0 = (tn / ntn) * 32, n0 = (tn % ntn) * 32;
    __shared__ float tile[32][33];
    const int tx = threadIdx.x & 31, ty = threadIdx.x >> 5;
    #pragma unroll
    for (int i = 0; i < 4; ++i)
        tile[ty + i * 8][tx] = src[(size_t)(k0 + ty + i * 8) * Nd + n0 + tx];
    __syncthreads();
    #pragma unroll
    for (int i = 0; i < 4; ++i)
        dst[(size_t)(n0 + ty + i * 8) * Kd + k0 + tx] = f2bf(tile[tx][ty + i * 8]);
}

// ---------------------------------------------------------------------------
// bf16 MFMA GEMM (m97 structure): C[M,N] = A[M,K] @ Bt[N,K]^T.
// MODE 0: C fp32.
// MODE 4: fused QKV epilogue — N=3072 over contiguous wqT|wkT|wvT.
//         (simple bf16 writes; norm/rope stays in its own kernel — r8 showed
//          in-GEMM norm+rope costs 55us of uncoalesced fc/fs loads.)
// ---------------------------------------------------------------------------
template<int MODE>
__global__ __launch_bounds__(256) void gemm_bf16(
    const short* __restrict__ A, const short* __restrict__ Bt,
    void* __restrict__ Cv, void* __restrict__ Cv2, int M, int N, int K)
{
    __shared__ short As[128 * 32];
    __shared__ short Bs[128 * 32];

    const int tid  = threadIdx.x;
    const int w    = tid >> 6;
    const int lane = tid & 63;
    const int quad = lane >> 4;
    const int n16  = lane & 15;
    const int m0 = blockIdx.y * 128;
    const int n0 = blockIdx.x * 128;
    const int wm = (w >> 1) * 64;
    const int wn = (w & 1) * 64;

    f32x4 acc[4][4];
    #pragma unroll
    for (int i = 0; i < 4; ++i)
        #pragma unroll
        for (int j = 0; j < 4; ++j) acc[i][j] = (f32x4){0.f, 0.f, 0.f, 0.f};

    for (int k0 = 0; k0 < K; k0 += 32) {
        __syncthreads();
        #pragma unroll
        for (int c = 0; c < 2; ++c) {
            int f = c * 2048 + tid * 8;
            int r = f >> 5, cc = f & 31;
            GLD_LDS16(A  + (size_t)(m0 + r) * K + k0 + cc, As + c * 2048 + w * 512);
            GLD_LDS16(Bt + (size_t)(n0 + r) * K + k0 + cc, Bs + c * 2048 + w * 512);
        }
        __syncthreads();

        bf16x8 af[4], bf[4];
        #pragma unroll
        for (int i = 0; i < 4; ++i) {
            af[i] = *reinterpret_cast<const bf16x8*>(&As[(wm + i * 16 + n16) * 32 + quad * 8]);
            bf[i] = *reinterpret_cast<const bf16x8*>(&Bs[(wn + i * 16 + n16) * 32 + quad * 8]);
        }
        #pragma unroll
        for (int mi = 0; mi < 4; ++mi)
            #pragma unroll
            for (int ni = 0; ni < 4; ++ni)
                acc[mi][ni] = __builtin_amdgcn_mfma_f32_16x16x32_bf16(
                    af[mi], bf[ni], acc[mi][ni], 0, 0, 0);
    }

    if (MODE == 0) {
        float* C = (float*)Cv;
        #pragma unroll
        for (int mi = 0; mi < 4; ++mi)
            #pragma unroll
            for (int ni = 0; ni < 4; ++ni)
                #pragma unroll
                for (int r = 0; r < 4; ++r)
                    C[(size_t)(m0 + wm + mi * 16 + quad * 4 + r) * N
                      + n0 + wn + ni * 16 + n16] = acc[mi][ni][r];
    } else { // MODE 4
        if (n0 < 2048) {
            short* Cq = (short*)Cv;
            #pragma unroll
            for (int mi = 0; mi < 4; ++mi)
                #pragma unroll
                for (int ni = 0; ni < 4; ++ni)
                    #pragma unroll
                    for (int r = 0; r < 4; ++r)
                        Cq[(size_t)(m0 + wm + mi * 16 + quad * 4 + r) * 2048
                           + n0 + wn + ni * 16 + n16] = f2bf(acc[mi][ni][r]);
        } else {
            short* Ck  = (short*)Cv2;
            short* Cvt = (short*)Cv2 + (size_t)B * T * KV * HD;  // vtb contiguous after kbuf
            #pragma unroll
            for (int mi = 0; mi < 4; ++mi) {
                int mrow = m0 + wm + mi * 16 + quad * 4;
                int bb = mrow >> 11;
                int t0 = mrow & (T - 1);
                #pragma unroll
                for (int ni = 0; ni < 4; ++ni) {
                    int n = n0 + wn + ni * 16 + n16 - 2048;   // 0..1023
                    if (n < 512) {
                        #pragma unroll
                        for (int r = 0; r < 4; ++r)
                            Ck[(size_t)(mrow + r) * 512 + n] = f2bf(acc[mi][ni][r]);
                    } else {
                        bf16x4 p;
                        p[0] = f2bf(acc[mi][ni][0]); p[1] = f2bf(acc[mi][ni][1]);
                        p[2] = f2bf(acc[mi][ni][2]); p[3] = f2bf(acc[mi][ni][3]);
                        *reinterpret_cast<bf16x4*>(
                            &Cvt[((size_t)bb * 512 + (n - 512)) * T + t0]) = p;
                    }
                }
            }
        }
    }
}

// ---------------------------------------------------------------------------
// RMSNorm + RoPE on bf16 q and k (in place). One wave per head-row.
// (Kept standalone: wave-per-row gives coalesced fc/fs loads — r8 proved the
//  in-GEMM fusion of this costs 4x more than the kernel itself.)
// ---------------------------------------------------------------------------
__global__ __launch_bounds__(256) void norm_rope(
    short* __restrict__ q, short* __restrict__ k,
    const float* __restrict__ qw, const float* __restrict__ kw,
    const float* __restrict__ fcos, const float* __restrict__ fsin)
{
    const int wid  = (blockIdx.x * blockDim.x + threadIdx.x) >> 6;
    const int lane = threadIdx.x & 63;
    const int QROWS = B * T * H;

    short* base;
    const float* w;
    int t;
    float scale;
    if (wid < QROWS) {
        t = (wid / H) % T;
        base = q + (size_t)wid * HD;
        w = qw;
        scale = QSCALE;
    } else {
        int rr = wid - QROWS;
        t = (rr / KV) % T;
        base = k + (size_t)rr * HD;
        w = kw;
        scale = 1.0f;
    }

    int pv = *reinterpret_cast<const int*>(&base[2 * lane]);
    float e = bf2f((short)(pv & 0xffff));
    float o = bf2f((short)(pv >> 16));

    float ss = e * e + o * o;
    #pragma unroll
    for (int off = 32; off; off >>= 1) ss += __shfl_xor(ss, off);

    const float rinv = rsqrtf(ss * (1.0f / HD) + 1e-6f);
    e *= rinv * w[2 * lane];
    o *= rinv * w[2 * lane + 1];

    const float c = fcos[t * (HD / 2) + lane];
    const float s = fsin[t * (HD / 2) + lane];
    const float eo = (e * c - o * s) * scale;
    const float oo = (e * s + o * c) * scale;
    int out = ((int)(unsigned short)f2bf(oo) << 16) | (unsigned short)f2bf(eo);
    *reinterpret_cast<int*>(&base[2 * lane]) = out;
}

// ---------------------------------------------------------------------------
// MFMA flash attention v11 = v9 attention path (verified 88.5us) + wo
// transpose-cvt folded in as blocks 512..2559 (verified harmless in r8).
// attn blocks first in the grid: critical qb=15 block starts at t=0;
// transpose blocks backfill idle CU slots during attn's imbalanced tail.
// ---------------------------------------------------------------------------
__global__ __launch_bounds__(512, 4) void attn_mfma(
    short* qob, const short* __restrict__ kb_, const short* __restrict__ vtb,
    const float* __restrict__ wo_, short* __restrict__ woT_)
{
    __shared__ short Ks[2][64 * 128];   // 32KB: [key][hd], 16B-chunk swz by key&7
    __shared__ short Vt[2][128 * 64];   // 32KB: [hd][key], 16B-chunk swz by hd&7
    __shared__ short Pl[4][32 * 64];    // 8KB

    const int tid = threadIdx.x;
    const int bid = blockIdx.x;

    if (bid >= 512) {
        // ---- wo transpose-cvt: 2048 blocks x 2 tiles (32x32), 512 threads ----
        float* tileb = reinterpret_cast<float*>(&Ks[0][0]);   // 2 x 32x33 f32
        const int half = tid >> 8;
        const int tl   = tid & 255;
        const int tx = tl & 31, ty = tl >> 5;                 // ty 0..7
        const int tn = (bid - 512) * 2 + half;                // 0..4095
        const int k0 = (tn >> 6) * 32, n0t = (tn & 63) * 32;
        float* tile = tileb + half * (32 * 33);
        #pragma unroll
        for (int i = 0; i < 4; ++i)
            tile[(ty + i * 8) * 33 + tx] =
                wo_[(size_t)(k0 + ty + i * 8) * 2048 + n0t + tx];
        __syncthreads();
        #pragma unroll
        for (int i = 0; i < 4; ++i)
            woT_[(size_t)(n0t + ty + i * 8) * 2048 + k0 + tx] =
                f2bf(tile[tx * 33 + ty + i * 8]);
        return;
    }

    const int w    = tid >> 6;      // 0..7
    const int w4   = w & 3;         // q-group (32 q-rows)
    const int kh   = w >> 2;        // half-split index
    const int lane = tid & 63;
    const int q4   = lane >> 4;
    const int n16  = lane & 15;

    int qb;
    if (bid < 256) qb = 15 - (bid >> 5);    // heavy half: qb 15..8
    else           qb = (bid - 256) >> 5;   // light half: qb 0..7
    const int h = bid & 15;
    const int b = (bid >> 4) & 1;
    const int g = h >> 2;

    // Q fragments (B-operand): 2 m-sets of 16 queries, QSCALE pre-folded
    bf16x8 qf[2][4];
    #pragma unroll
    for (int m = 0; m < 2; ++m) {
        const int qrow = qb * 128 + w4 * 32 + m * 16 + n16;
        const short* qp = qob + ((size_t)(b * T + qrow) * H + h) * HD;
        #pragma unroll
        for (int c = 0; c < 4; ++c)
            qf[m][c] = *reinterpret_cast<const bf16x8*>(qp + c * 32 + q4 * 8);
    }

    f32x4 oa[2][4];
    #pragma unroll
    for (int m = 0; m < 2; ++m)
        #pragma unroll
        for (int nl = 0; nl < 4; ++nl) oa[m][nl] = (f32x4){0.f, 0.f, 0.f, 0.f};
    float l0 = 0.f, l1 = 0.f;

    short* preg = &Pl[w4][0];

    // staging lane mapping (512 threads, 2 issues each of K and V per iter)
    const int kr  = lane >> 4;                  // K: 4 rows per wave-issue
    const int kc_ = lane & 15;
    const int vr  = lane >> 3;                  // V: 8 rows per wave-issue
    const int vc_ = lane & 7;

    const short* kgb = kb_ + (size_t)b * T * KV * HD + (size_t)g * HD;
    const short* vgb = vtb + ((size_t)(b * KV + g) * HD) * T;

    auto STAGE_K = [&](int bb, int kb) {
        short* KsB = &Ks[bb][0];
        #pragma unroll
        for (int i = 0; i < 2; ++i) {
            const int grow = (i * 8 + w) * 4 + kr;          // 0..63
            const int cs   = kc_ ^ (grow & 7);
            GLD_LDS16(kgb + (size_t)(kb * 64 + grow) * (KV * HD) + cs * 8,
                      KsB + (i * 8 + w) * 512);
        }
    };
    auto STAGE_V = [&](int bb, int kb) {
        short* VtB = &Vt[bb][0];
        #pragma unroll
        for (int i = 0; i < 2; ++i) {
            const int hd = (i * 8 + w) * 8 + vr;            // 0..127
            const int cs = vc_ ^ (hd & 7);
            GLD_LDS16(vgb + (size_t)hd * T + kb * 64 + cs * 8,
                      VtB + (i * 8 + w) * 512);
        }
    };

    const int nkb = 2 * qb + 2;  // 64-key tiles covering keys [0, (qb+1)*128)
    int cur = 0;

    // prologue: stage K(0), V(0), drain, sync
    STAGE_K(0, 0);
    STAGE_V(0, 0);
    asm volatile("s_waitcnt vmcnt(0)" ::: "memory");
    __builtin_amdgcn_sched_barrier(0);
    __builtin_amdgcn_s_barrier();
    __builtin_amdgcn_sched_barrier(0);

    for (int kb = 0; kb < nkb; ++kb) {
        // issue next tile's K AND V into the other buffer (drained at end bar)
        const bool pf = (kb + 1 < nkb);
        if (pf) {
            STAGE_V(cur ^ 1, kb + 1);
            STAGE_K(cur ^ 1, kb + 1);
        }

        const int kof = kb * 64 - qb * 128;   // local key offset (>=0 only near diag)
        const short* KsB = &Ks[cur][0];
        const short* VtB = &Vt[cur][0];

        // ---- S^T = K @ Q^T over this wave's key-half (kt = kh*2 + kt') ----
        f32x4 s[2][2];
        #pragma unroll
        for (int m = 0; m < 2; ++m)
            #pragma unroll
            for (int kt = 0; kt < 2; ++kt) s[m][kt] = (f32x4){0.f, 0.f, 0.f, 0.f};

        __builtin_amdgcn_s_setprio(1);
        #pragma unroll
        for (int cc = 0; cc < 4; ++cc) {
            const int gk = (4 * cc + q4) ^ (n16 & 7);
            #pragma unroll
            for (int kt = 0; kt < 2; ++kt) {
                const int ktg = kh * 2 + kt;
                bf16x8 kf = *reinterpret_cast<const bf16x8*>(
                    &KsB[(ktg * 16 + n16) * 128 + gk * 8]);
                if (!(kof + ktg * 16 > w4 * 32 + 15))
                    s[0][kt] = __builtin_amdgcn_mfma_f32_16x16x32_bf16(kf, qf[0][cc], s[0][kt], 0, 0, 0);
                if (!(kof + ktg * 16 > w4 * 32 + 31))
                    s[1][kt] = __builtin_amdgcn_mfma_f32_16x16x32_bf16(kf, qf[1][cc], s[1][kt], 0, 0, 0);
            }
        }
        __builtin_amdgcn_s_setprio(0);

        // ---- causal mask (diagonal tiles only) ----
        if (kof >= 0) {
            #pragma unroll
            for (int m = 0; m < 2; ++m) {
                const int qloc = w4 * 32 + m * 16 + n16;
                #pragma unroll
                for (int kt = 0; kt < 2; ++kt)
                    #pragma unroll
                    for (int r = 0; r < 4; ++r)
                        if (kof + (kh * 2 + kt) * 16 + q4 * 4 + r > qloc)
                            s[m][kt][r] = -1e30f;
            }
        }

        // ---- static-max softmax in place: s := exp2(s); accumulate l ----
        #pragma unroll
        for (int kt = 0; kt < 2; ++kt) {
            #pragma unroll
            for (int r = 0; r < 4; ++r) {
                s[0][kt][r] = exp2f(s[0][kt][r]);
                s[1][kt][r] = exp2f(s[1][kt][r]);
            }
            l0 += (s[0][kt][0] + s[0][kt][1]) + (s[0][kt][2] + s[0][kt][3]);
            l1 += (s[1][kt][0] + s[1][kt][1]) + (s[1][kt][2] + s[1][kt][3]);
        }

        // ---- pack P -> shared per-q-group buffer (this wave's key-half) ----
        #pragma unroll
        for (int m = 0; m < 2; ++m) {
            const int row = m * 16 + n16;
            #pragma unroll
            for (int kt = 0; kt < 2; ++kt) {
                const int c = kh * 4 + kt * 2 + (q4 >> 1);
                u32x2 wv;
                wv[0] = pk_trunc(s[m][kt][0], s[m][kt][1]);
                wv[1] = pk_trunc(s[m][kt][2], s[m][kt][3]);
                *reinterpret_cast<u32x2*>(
                    &preg[row * 64 + (c ^ (n16 & 7)) * 8 + (q4 & 1) * 4]) = wv;
            }
        }

        // ---- mid barrier (drain-free): P visible to partner wave ----
        asm volatile("s_waitcnt lgkmcnt(0)" ::: "memory");
        __builtin_amdgcn_sched_barrier(0);
        __builtin_amdgcn_s_barrier();
        __builtin_amdgcn_sched_barrier(0);

        // ---- P @ V: full 64 keys, this wave's hd-half (nt = kh*4 + nl) ----
        __builtin_amdgcn_s_setprio(1);
        #pragma unroll
        for (int kc = 0; kc < 2; ++kc) {
            const bool u0 = !(kof + kc * 32 > w4 * 32 + 15);
            const bool u1 = !(kof + kc * 32 > w4 * 32 + 31);
            if (u0 | u1) {
                const int gp = ((kc * 4 + q4) ^ (n16 & 7)) * 8;
                bf16x8 af0 = *reinterpret_cast<const bf16x8*>(&preg[n16 * 64 + gp]);
                bf16x8 af1 = *reinterpret_cast<const bf16x8*>(&preg[(16 + n16) * 64 + gp]);
                #pragma unroll
                for (int nl = 0; nl < 4; ++nl) {
                    const int nt = kh * 4 + nl;
                    bf16x8 vf = *reinterpret_cast<const bf16x8*>(
                        &VtB[(nt * 16 + n16) * 64 + gp]);
                    if (u0)
                        oa[0][nl] = __builtin_amdgcn_mfma_f32_16x16x32_bf16(af0, vf, oa[0][nl], 0, 0, 0);
                    if (u1)
                        oa[1][nl] = __builtin_amdgcn_mfma_f32_16x16x32_bf16(af1, vf, oa[1][nl], 0, 0, 0);
                }
            }
        }
        __builtin_amdgcn_s_setprio(0);

        // ---- end barrier: next tile's K+V landed; buffers release ----
        asm volatile("s_waitcnt vmcnt(0)" ::: "memory");
        __builtin_amdgcn_sched_barrier(0);
        __builtin_amdgcn_s_barrier();
        __builtin_amdgcn_sched_barrier(0);
        cur ^= 1;
    }

    // ---- epilogue: reduce l over q4, combine key-halves, O = oa / l ----
    l0 += __shfl_xor(l0, 16); l0 += __shfl_xor(l0, 32);
    l1 += __shfl_xor(l1, 16); l1 += __shfl_xor(l1, 32);

    float* Lsh = (float*)&Pl[0][0];
    if (q4 == 0) {
        Lsh[w * 32 + n16] = l0;
        Lsh[w * 32 + 16 + n16] = l1;
    }
    __syncthreads();
    l0 += Lsh[(w ^ 4) * 32 + n16];
    l1 += Lsh[(w ^ 4) * 32 + 16 + n16];

    #pragma unroll
    for (int m = 0; m < 2; ++m) {
        #pragma unroll
        for (int r = 0; r < 4; ++r) {
            const float lr = __shfl(m == 0 ? l0 : l1, q4 * 20 + r);
            const float inv = 1.0f / lr;
            const int row = qb * 128 + w4 * 32 + m * 16 + q4 * 4 + r;
            short* op = qob + ((size_t)(b * T + row) * H + h) * HD;
            #pragma unroll
            for (int nl = 0; nl < 4; ++nl)
                op[(kh * 4 + nl) * 16 + n16] = f2bf(oa[m][nl][r] * inv);
        }
    }
}

// ---------------------------------------------------------------------------
extern "C" void kernel_launch(void* const* d_in, const int* in_sizes, int n_in,
                              void* d_out, int out_size, void* d_ws, size_t ws_size,
                              hipStream_t stream) {
    const float* x  = (const float*)d_in[0];
    const float* wq = (const float*)d_in[1];
    const float* wk = (const float*)d_in[2];
    const float* wv = (const float*)d_in[3];
    const float* wo = (const float*)d_in[4];
    const float* qw = (const float*)d_in[5];
    const float* kw = (const float*)d_in[6];
    const float* fc = (const float*)d_in[7];
    const float* fs = (const float*)d_in[8];
    float* out = (float*)d_out;

    short* xb   = (short*)d_ws;                      // B*T*D
    short* wqT  = xb   + (size_t)B * T * D;          // D*D
    short* wkT  = wqT  + (size_t)D * D;              // 512*D (contiguous after wqT)
    short* wvT  = wkT  + (size_t)(KV * HD) * D;      // 512*D (contiguous after wkT)
    short* qbuf = wvT  + (size_t)(KV * HD) * D;      // B*T*H*HD
    short* kbuf = qbuf + (size_t)B * T * H * HD;     // B*T*KV*HD
    short* vtb  = kbuf + (size_t)B * T * KV * HD;    // B*KV*HD*T (contiguous after kbuf)
    short* woT  = xb;                                // alias: xb dead after QKV GEMM

    const int M = B * T;   // 4096
    dim3 blk(256);

    // 1) prep: x convert + wq/wk/wv transpose
    prep<<<dim3(10240), blk, 0, stream>>>(x, wq, wk, wv, xb, wqT, wkT, wvT);

    // 2) fused Q|K|V GEMM (simple epilogue)
    gemm_bf16<4><<<dim3(3072 / 128, M / 128), blk, 0, stream>>>(
        xb, wqT, (void*)qbuf, (void*)kbuf, M, 3072, D);

    // 3) RMSNorm + RoPE (standalone: coalesced fc/fs access)
    {
        int waves = B * T * (H + KV);
        norm_rope<<<dim3((waves * 64) / 256), blk, 0, stream>>>(
            qbuf, kbuf, qw, kw, fc, fs);
    }

    // 4) attention + wo transpose-cvt (blocks 512..2559)
    attn_mfma<<<dim3(2560), dim3(512), 0, stream>>>(qbuf, kbuf, vtb, wo, woT);

    // 5) output GEMM
    gemm_bf16<0><<<dim3(D / 128, M / 128), blk, 0, stream>>>(
        qbuf, woT, (void*)out, nullptr, M, D, H * HD);
}